// Round 1
// baseline (543.261 us; speedup 1.0000x reference)
//
#include <hip/hip_runtime.h>

#define N_NODES 10000
#define DIM 512
#define NE 160000

// ---------------- CSR construction ----------------

__global__ __launch_bounds__(256) void hist_kernel(const int* __restrict__ dst,
                                                   int* __restrict__ deg, int E) {
  int e = blockIdx.x * 256 + threadIdx.x;
  if (e < E) atomicAdd(&deg[dst[e]], 1);
}

__global__ __launch_bounds__(256) void scan_kernel(const int* __restrict__ deg,
                                                   int* __restrict__ rowptr,
                                                   int* __restrict__ cursor) {
  __shared__ int partial[256];
  const int CH = 40;  // 256*40 = 10240 >= 10000
  int tid = threadIdx.x;
  int start = tid * CH;
  int sum = 0;
  for (int i = 0; i < CH; ++i) {
    int idx = start + i;
    if (idx < N_NODES) sum += deg[idx];
  }
  partial[tid] = sum;
  __syncthreads();
  if (tid == 0) {
    int run = 0;
    for (int i = 0; i < 256; ++i) { int t = partial[i]; partial[i] = run; run += t; }
  }
  __syncthreads();
  int off = partial[tid];
  for (int i = 0; i < CH; ++i) {
    int idx = start + i;
    if (idx < N_NODES) {
      rowptr[idx] = off;
      cursor[idx] = off;
      off += deg[idx];
    }
  }
  if (tid == 255) rowptr[N_NODES] = off;  // chunk 255 is entirely past N_NODES
}

__global__ __launch_bounds__(256) void scatter_kernel(const int* __restrict__ src,
                                                      const int* __restrict__ dst,
                                                      const float* __restrict__ ew,
                                                      int* __restrict__ cursor,
                                                      int* __restrict__ s_src,
                                                      float* __restrict__ s_ew, int E) {
  int e = blockIdx.x * 256 + threadIdx.x;
  if (e < E) {
    int d = dst[e];
    int p = atomicAdd(&cursor[d], 1);
    s_src[p] = src[e];
    s_ew[p] = ew[e];
  }
}

// ---------------- mean aggregation: one wave per node ----------------

__global__ __launch_bounds__(256) void aggregate_kernel(const float* __restrict__ in,
                                                        const int* __restrict__ rowptr,
                                                        const int* __restrict__ s_src,
                                                        const float* __restrict__ s_ew,
                                                        float* __restrict__ agg) {
  int wid = (blockIdx.x * blockDim.x + threadIdx.x) >> 6;
  int lane = threadIdx.x & 63;
  if (wid >= N_NODES) return;
  int beg = rowptr[wid], end = rowptr[wid + 1];
  float a0 = 0, a1 = 0, a2 = 0, a3 = 0, b0 = 0, b1 = 0, b2 = 0, b3 = 0;
  for (int k = beg; k < end; ++k) {
    int s = s_src[k];
    float w = s_ew[k];
    const float4* p = (const float4*)(in + (size_t)s * DIM);
    float4 v0 = p[lane];
    float4 v1 = p[lane + 64];
    a0 += v0.x * w; a1 += v0.y * w; a2 += v0.z * w; a3 += v0.w * w;
    b0 += v1.x * w; b1 += v1.y * w; b2 += v1.z * w; b3 += v1.w * w;
  }
  float inv = 1.0f / fmaxf((float)(end - beg), 1.0f);
  float4 o0 = {a0 * inv, a1 * inv, a2 * inv, a3 * inv};
  float4 o1 = {b0 * inv, b1 * inv, b2 * inv, b3 * inv};
  float4* q = (float4*)(agg + (size_t)wid * DIM);
  q[lane] = o0;
  q[lane + 64] = o1;
}

// ---------------- dual-A f32 tiled GEMM: out = A1@W1 (+ A2@W2) (+bias) (relu) ----
// BM=64, BN=64, BK=16, 256 threads, 4x4 per thread.

#define BM 64
#define BN 64
#define BK 16

__global__ __launch_bounds__(256) void gemm_dual(const float* __restrict__ A1,
                                                 const float* __restrict__ W1,
                                                 const float* __restrict__ A2,
                                                 const float* __restrict__ W2,
                                                 const float* __restrict__ bias,
                                                 float* __restrict__ out, int M, int K,
                                                 int ldW, int ldOut, int relu) {
  __shared__ float sA[BK][BM + 4];
  __shared__ float sB[BK][BN + 4];
  int bm = blockIdx.x * BM;
  int bn = blockIdx.y * BN;
  int tid = threadIdx.x;
  int tx = tid & 15, ty = tid >> 4;

  float acc[4][4] = {};

  int ar = tid >> 2;        // A row in tile 0..63
  int ac = (tid & 3) * 4;   // A col in tile 0,4,8,12
  int br = tid >> 4;        // B row in tile 0..15
  int bc = (tid & 15) * 4;  // B col in tile

  for (int pass = 0; pass < 2; ++pass) {
    const float* A = pass ? A2 : A1;
    const float* W = pass ? W2 : W1;
    if (!A) break;
    for (int k0 = 0; k0 < K; k0 += BK) {
      __syncthreads();
      {
        int row = bm + ar;
        float4 v = {0, 0, 0, 0};
        if (row < M) v = *(const float4*)(A + (size_t)row * K + k0 + ac);
        sA[ac + 0][ar] = v.x;
        sA[ac + 1][ar] = v.y;
        sA[ac + 2][ar] = v.z;
        sA[ac + 3][ar] = v.w;
      }
      {
        float4 v = *(const float4*)(W + (size_t)(k0 + br) * ldW + bn + bc);
        *(float4*)&sB[br][bc] = v;
      }
      __syncthreads();
#pragma unroll
      for (int k = 0; k < BK; ++k) {
        float4 a = *(const float4*)&sA[k][ty * 4];
        float4 b = *(const float4*)&sB[k][tx * 4];
        float av[4] = {a.x, a.y, a.z, a.w};
        float bv[4] = {b.x, b.y, b.z, b.w};
#pragma unroll
        for (int i = 0; i < 4; ++i)
#pragma unroll
          for (int j = 0; j < 4; ++j) acc[i][j] += av[i] * bv[j];
      }
    }
  }

#pragma unroll
  for (int i = 0; i < 4; ++i) {
    int row = bm + ty * 4 + i;
    if (row >= M) continue;
    float4 v;
    float* vp = (float*)&v;
#pragma unroll
    for (int j = 0; j < 4; ++j) {
      float t = acc[i][j];
      if (bias) t += bias[bn + tx * 4 + j];
      if (relu) t = fmaxf(t, 0.0f);
      vp[j] = t;
    }
    *(float4*)(out + (size_t)row * ldOut + bn + tx * 4) = v;
  }
}

// ---------------- edge decoder: one wave per edge ----------------

__global__ __launch_bounds__(256) void decode_kernel(const float* __restrict__ AB,
                                                     const int* __restrict__ eli,
                                                     const float* __restrict__ expw,
                                                     const float* __restrict__ wrow,
                                                     const float* __restrict__ bd1,
                                                     const float* __restrict__ Wd2,
                                                     const float* __restrict__ bd2,
                                                     float* __restrict__ out, int E) {
  int wid = blockIdx.x * 4 + (threadIdx.x >> 6);
  int j = threadIdx.x & 63;
  if (wid >= E) return;
  int s = eli[wid];
  int d = eli[E + wid];
  float v = AB[(size_t)s * 128 + j] + AB[(size_t)d * 128 + 64 + j] +
            expw[wid] * wrow[j] + bd1[j];
  float h = fmaxf(v, 0.0f);
  float p = h * Wd2[j];
#pragma unroll
  for (int off = 32; off >= 1; off >>= 1) p += __shfl_xor(p, off);
  if (j == 0) out[wid] = p + bd2[0];
}

// ---------------- launcher ----------------

extern "C" void kernel_launch(void* const* d_in, const int* in_sizes, int n_in,
                              void* d_out, int out_size, void* d_ws, size_t ws_size,
                              hipStream_t stream) {
  const float* x    = (const float*)d_in[0];
  const float* ew   = (const float*)d_in[1];
  const float* expw = (const float*)d_in[2];
  const float* W1r  = (const float*)d_in[3];
  const float* b1   = (const float*)d_in[4];
  const float* W1o  = (const float*)d_in[5];
  const float* W2r  = (const float*)d_in[6];
  const float* b2   = (const float*)d_in[7];
  const float* W2o  = (const float*)d_in[8];
  const float* Wd1  = (const float*)d_in[9];
  const float* bd1  = (const float*)d_in[10];
  const float* Wd2  = (const float*)d_in[11];
  const float* bd2  = (const float*)d_in[12];
  const int* ei     = (const int*)d_in[13];
  const int* eli    = (const int*)d_in[14];
  float* out = (float*)d_out;

  char* ws = (char*)d_ws;
  int* deg      = (int*)(ws + 0);           // 10000 ints
  int* rowptr   = (int*)(ws + 40000);       // 10001 ints (padded)
  int* cursor   = (int*)(ws + 80064);       // 10000 ints
  int* s_src    = (int*)(ws + 120064);      // 160000 ints
  float* s_ew   = (float*)(ws + 760064);    // 160000 floats
  float* agg    = (float*)(ws + 1400064);   // 10000*512
  float* z1     = (float*)(ws + 21880064);  // 10000*512
  float* z2     = (float*)(ws + 42360064);  // 10000*512
  float* AB     = (float*)(ws + 62840064);  // 10000*128

  const int* src = ei;
  const int* dst = ei + NE;

  hipMemsetAsync(deg, 0, 40000, stream);
  hist_kernel<<<625, 256, 0, stream>>>(dst, deg, NE);
  scan_kernel<<<1, 256, 0, stream>>>(deg, rowptr, cursor);
  scatter_kernel<<<625, 256, 0, stream>>>(src, dst, ew, cursor, s_src, s_ew, NE);

  // layer 1
  aggregate_kernel<<<2500, 256, 0, stream>>>(x, rowptr, s_src, s_ew, agg);
  dim3 g1(157, 8);
  gemm_dual<<<g1, 256, 0, stream>>>(agg, W1r, x, W1o, b1, z1, N_NODES, DIM, DIM, DIM, 1);

  // layer 2
  aggregate_kernel<<<2500, 256, 0, stream>>>(z1, rowptr, s_src, s_ew, agg);
  gemm_dual<<<g1, 256, 0, stream>>>(agg, W2r, z1, W2o, b2, z2, N_NODES, DIM, DIM, DIM, 0);

  // decoder node-side precompute: AB[:,0:64] = z2 @ Wd1[0:512], AB[:,64:128] = z2 @ Wd1[512:1024]
  dim3 g2(157, 1);
  gemm_dual<<<g2, 256, 0, stream>>>(z2, Wd1, nullptr, nullptr, nullptr, AB, N_NODES, DIM,
                                    64, 128, 0);
  gemm_dual<<<g2, 256, 0, stream>>>(z2, Wd1 + 512 * 64, nullptr, nullptr, nullptr, AB + 64,
                                    N_NODES, DIM, 64, 128, 0);

  // per-edge decode
  decode_kernel<<<40000, 256, 0, stream>>>(AB, eli, expw, Wd1 + 1024 * 64, bd1, Wd2, bd2,
                                           out, NE);
}

// Round 2
// 350.512 us; speedup vs baseline: 1.5499x; 1.5499x over previous
//
#include <hip/hip_runtime.h>

#define N_NODES 10000
#define DIM 512
#define NE 160000

typedef short bf16x8 __attribute__((ext_vector_type(8)));
typedef float f32x4 __attribute__((ext_vector_type(4)));

__device__ __forceinline__ ushort f2bf(float f) {
  unsigned u = __float_as_uint(f);
  u += 0x7FFFu + ((u >> 16) & 1u);
  return (ushort)(u >> 16);
}
__device__ __forceinline__ float bf2f(ushort h) {
  return __uint_as_float(((unsigned)h) << 16);
}
__device__ __forceinline__ void gload16(const void* g, void* l) {
  __builtin_amdgcn_global_load_lds((const __attribute__((address_space(1))) void*)g,
                                   (__attribute__((address_space(3))) void*)l, 16, 0, 0);
}

// ---------------- CSR construction ----------------

__global__ __launch_bounds__(256) void hist_kernel(const int* __restrict__ dst,
                                                   int* __restrict__ deg, int E) {
  int e = blockIdx.x * 256 + threadIdx.x;
  if (e < E) atomicAdd(&deg[dst[e]], 1);
}

__global__ __launch_bounds__(256) void scan_kernel(const int* __restrict__ deg,
                                                   int* __restrict__ rowptr,
                                                   int* __restrict__ cursor) {
  __shared__ int partial[256];
  const int CH = 40;
  int tid = threadIdx.x;
  int start = tid * CH;
  int sum = 0;
  for (int i = 0; i < CH; ++i) {
    int idx = start + i;
    if (idx < N_NODES) sum += deg[idx];
  }
  partial[tid] = sum;
  __syncthreads();
  if (tid == 0) {
    int run = 0;
    for (int i = 0; i < 256; ++i) { int t = partial[i]; partial[i] = run; run += t; }
  }
  __syncthreads();
  int off = partial[tid];
  for (int i = 0; i < CH; ++i) {
    int idx = start + i;
    if (idx < N_NODES) {
      rowptr[idx] = off;
      cursor[idx] = off;
      off += deg[idx];
    }
  }
  if (tid == 255) rowptr[N_NODES] = off;
}

__global__ __launch_bounds__(256) void scatter_kernel(const int* __restrict__ src,
                                                      const int* __restrict__ dst,
                                                      const float* __restrict__ ew,
                                                      int* __restrict__ cursor,
                                                      int* __restrict__ s_src,
                                                      float* __restrict__ s_ew, int E) {
  int e = blockIdx.x * 256 + threadIdx.x;
  if (e < E) {
    int d = dst[e];
    int p = atomicAdd(&cursor[d], 1);
    s_src[p] = src[e];
    s_ew[p] = ew[e];
  }
}

// ---------------- conversion kernels ----------------

// split f32 -> (hi,lo) bf16, 4 elems/thread
__global__ __launch_bounds__(256) void split_f32(const float* __restrict__ src,
                                                 ushort* __restrict__ hi,
                                                 ushort* __restrict__ lo, int n4) {
  int i = blockIdx.x * 256 + threadIdx.x;
  if (i >= n4) return;
  float4 v = ((const float4*)src)[i];
  ushort4 h, l;
  h.x = f2bf(v.x); l.x = f2bf(v.x - bf2f(h.x));
  h.y = f2bf(v.y); l.y = f2bf(v.y - bf2f(h.y));
  h.z = f2bf(v.z); l.z = f2bf(v.z - bf2f(h.z));
  h.w = f2bf(v.w); l.w = f2bf(v.w - bf2f(h.w));
  ((ushort4*)hi)[i] = h;
  ((ushort4*)lo)[i] = l;
}

// transpose 512x512 f32 -> [N][K] bf16 hi/lo, 4 matrices selected by blockIdx.y
__global__ __launch_bounds__(256) void wtrans(const float* s0, const float* s1,
                                              const float* s2, const float* s3,
                                              ushort* h0, ushort* l0, ushort* h1, ushort* l1,
                                              ushort* h2, ushort* l2, ushort* h3, ushort* l3) {
  const float* src; ushort* dh; ushort* dl;
  switch (blockIdx.y) {
    case 0: src = s0; dh = h0; dl = l0; break;
    case 1: src = s1; dh = h1; dl = l1; break;
    case 2: src = s2; dh = h2; dl = l2; break;
    default: src = s3; dh = h3; dl = l3; break;
  }
  __shared__ float sT[64][65];
  int tile = blockIdx.x;
  int tr = tile >> 3, tc = tile & 7;  // 8x8 tiles of 64x64
  int tid = threadIdx.x;
  for (int i = 0; i < 16; ++i) {
    int lin = i * 256 + tid;
    int r = lin >> 6, c = lin & 63;
    sT[r][c] = src[(size_t)(tr * 64 + r) * 512 + tc * 64 + c];
  }
  __syncthreads();
  for (int i = 0; i < 16; ++i) {
    int lin = i * 256 + tid;
    int n = lin >> 6, k = lin & 63;
    float v = sT[k][n];
    ushort h = f2bf(v);
    ushort l = f2bf(v - bf2f(h));
    size_t o = (size_t)(tc * 64 + n) * 512 + tr * 64 + k;
    dh[o] = h;
    dl[o] = l;
  }
}

// build transposed combined decoder weight: Bt[j][k], j<64 -> Wd1[k][j], j>=64 -> Wd1[512+k][j-64]
__global__ __launch_bounds__(256) void wd1_build(const float* __restrict__ Wd1,
                                                 ushort* __restrict__ bh,
                                                 ushort* __restrict__ bl) {
  int lin = blockIdx.x * 256 + threadIdx.x;  // 128*512
  if (lin >= 128 * 512) return;
  int j = lin >> 9, k = lin & 511;
  float v = Wd1[(size_t)(j < 64 ? k : 512 + k) * 64 + (j & 63)];
  ushort h = f2bf(v);
  bh[lin] = h;
  bl[lin] = f2bf(v - bf2f(h));
}

// ---------------- mean aggregation: one wave per node, writes hi/lo ----------------

__global__ __launch_bounds__(256) void aggregate_split(const float* __restrict__ srcf,
                                                       const ushort* __restrict__ srch,
                                                       const ushort* __restrict__ srcl,
                                                       const int* __restrict__ rowptr,
                                                       const int* __restrict__ s_src,
                                                       const float* __restrict__ s_ew,
                                                       ushort* __restrict__ aggh,
                                                       ushort* __restrict__ aggl) {
  int wid = (blockIdx.x * blockDim.x + threadIdx.x) >> 6;
  int lane = threadIdx.x & 63;
  if (wid >= N_NODES) return;
  int beg = rowptr[wid], end = rowptr[wid + 1];
  float a0 = 0, a1 = 0, a2 = 0, a3 = 0, b0 = 0, b1 = 0, b2 = 0, b3 = 0;
  if (srcf) {
    for (int k = beg; k < end; ++k) {
      int s = s_src[k];
      float w = s_ew[k];
      const float4* p = (const float4*)(srcf + (size_t)s * DIM);
      float4 v0 = p[lane];
      float4 v1 = p[lane + 64];
      a0 += v0.x * w; a1 += v0.y * w; a2 += v0.z * w; a3 += v0.w * w;
      b0 += v1.x * w; b1 += v1.y * w; b2 += v1.z * w; b3 += v1.w * w;
    }
  } else {
    for (int k = beg; k < end; ++k) {
      int s = s_src[k];
      float w = s_ew[k];
      const ushort4* ph = (const ushort4*)(srch + (size_t)s * DIM);
      const ushort4* pl = (const ushort4*)(srcl + (size_t)s * DIM);
      ushort4 h0 = ph[lane], h1 = ph[lane + 64];
      ushort4 l0 = pl[lane], l1 = pl[lane + 64];
      a0 += (bf2f(h0.x) + bf2f(l0.x)) * w;
      a1 += (bf2f(h0.y) + bf2f(l0.y)) * w;
      a2 += (bf2f(h0.z) + bf2f(l0.z)) * w;
      a3 += (bf2f(h0.w) + bf2f(l0.w)) * w;
      b0 += (bf2f(h1.x) + bf2f(l1.x)) * w;
      b1 += (bf2f(h1.y) + bf2f(l1.y)) * w;
      b2 += (bf2f(h1.z) + bf2f(l1.z)) * w;
      b3 += (bf2f(h1.w) + bf2f(l1.w)) * w;
    }
  }
  float inv = 1.0f / fmaxf((float)(end - beg), 1.0f);
  float o[8] = {a0 * inv, a1 * inv, a2 * inv, a3 * inv,
                b0 * inv, b1 * inv, b2 * inv, b3 * inv};
  ushort4 h0, h1, l0, l1;
  h0.x = f2bf(o[0]); l0.x = f2bf(o[0] - bf2f(h0.x));
  h0.y = f2bf(o[1]); l0.y = f2bf(o[1] - bf2f(h0.y));
  h0.z = f2bf(o[2]); l0.z = f2bf(o[2] - bf2f(h0.z));
  h0.w = f2bf(o[3]); l0.w = f2bf(o[3] - bf2f(h0.w));
  h1.x = f2bf(o[4]); l1.x = f2bf(o[4] - bf2f(h1.x));
  h1.y = f2bf(o[5]); l1.y = f2bf(o[5] - bf2f(h1.y));
  h1.z = f2bf(o[6]); l1.z = f2bf(o[6] - bf2f(h1.z));
  h1.w = f2bf(o[7]); l1.w = f2bf(o[7] - bf2f(h1.w));
  ushort4* qh = (ushort4*)(aggh + (size_t)wid * DIM);
  ushort4* ql = (ushort4*)(aggl + (size_t)wid * DIM);
  qh[lane] = h0; qh[lane + 64] = h1;
  ql[lane] = l0; ql[lane + 64] = l1;
}

// ---------------- MFMA GEMM: out = sum_seg (A_seg @ B_seg) via 3-term bf16 split ------
// A: [M][512] bf16 hi/lo row-major. B: [N][512] bf16 hi/lo (transposed weights).
// 128x128 tile, 4 waves (2x2 of 64x64), BK=32, K=512 fixed.

__global__ __launch_bounds__(256) void gemm_mfma(
    const ushort* __restrict__ A1h, const ushort* __restrict__ A1l,
    const ushort* __restrict__ B1h, const ushort* __restrict__ B1l,
    const ushort* __restrict__ A2h, const ushort* __restrict__ A2l,
    const ushort* __restrict__ B2h, const ushort* __restrict__ B2l,
    const float* __restrict__ bias, float* __restrict__ outf,
    ushort* __restrict__ outh, ushort* __restrict__ outl,
    int M, int ldout, int relu) {
  __shared__ ushort sAh[128][32];
  __shared__ ushort sAl[128][32];
  __shared__ ushort sBh[128][32];
  __shared__ ushort sBl[128][32];

  int tid = threadIdx.x;
  int w = tid >> 6, l = tid & 63;
  int bm = blockIdx.x * 128, bn = blockIdx.y * 128;
  int wr = w >> 1, wc = w & 1;

  f32x4 acc[4][4] = {};

  int srow = w * 16 + (l >> 2);   // staging row within 64-row half
  int scol = (l & 3) * 8;         // bf16 offset within 32-wide row

  for (int seg = 0; seg < 2; ++seg) {
    const ushort* Ah = seg ? A2h : A1h;
    const ushort* Al = seg ? A2l : A1l;
    const ushort* Bh = seg ? B2h : B1h;
    const ushort* Bl = seg ? B2l : B1l;
    if (!Ah) break;
    for (int k0 = 0; k0 < 512; k0 += 32) {
      __syncthreads();
      int r0 = bm + srow;       if (r0 > M - 1) r0 = M - 1;
      int r1 = bm + 64 + srow;  if (r1 > M - 1) r1 = M - 1;
      int n0 = bn + srow;
      int n1 = bn + 64 + srow;
      gload16(Ah + (size_t)r0 * 512 + k0 + scol, (char*)sAh + w * 1024);
      gload16(Ah + (size_t)r1 * 512 + k0 + scol, (char*)sAh + 4096 + w * 1024);
      gload16(Al + (size_t)r0 * 512 + k0 + scol, (char*)sAl + w * 1024);
      gload16(Al + (size_t)r1 * 512 + k0 + scol, (char*)sAl + 4096 + w * 1024);
      gload16(Bh + (size_t)n0 * 512 + k0 + scol, (char*)sBh + w * 1024);
      gload16(Bh + (size_t)n1 * 512 + k0 + scol, (char*)sBh + 4096 + w * 1024);
      gload16(Bl + (size_t)n0 * 512 + k0 + scol, (char*)sBl + w * 1024);
      gload16(Bl + (size_t)n1 * 512 + k0 + scol, (char*)sBl + 4096 + w * 1024);
      __syncthreads();

      int rsel = l & 15, ksel = (l >> 4) * 8;
      bf16x8 fAh[4], fAl[4], fBh[4], fBl[4];
#pragma unroll
      for (int i = 0; i < 4; ++i) {
        fAh[i] = *(const bf16x8*)&sAh[wr * 64 + i * 16 + rsel][ksel];
        fAl[i] = *(const bf16x8*)&sAl[wr * 64 + i * 16 + rsel][ksel];
      }
#pragma unroll
      for (int j = 0; j < 4; ++j) {
        fBh[j] = *(const bf16x8*)&sBh[wc * 64 + j * 16 + rsel][ksel];
        fBl[j] = *(const bf16x8*)&sBl[wc * 64 + j * 16 + rsel][ksel];
      }
#pragma unroll
      for (int i = 0; i < 4; ++i)
#pragma unroll
        for (int j = 0; j < 4; ++j) {
          acc[i][j] = __builtin_amdgcn_mfma_f32_16x16x32_bf16(fAh[i], fBh[j], acc[i][j], 0, 0, 0);
          acc[i][j] = __builtin_amdgcn_mfma_f32_16x16x32_bf16(fAh[i], fBl[j], acc[i][j], 0, 0, 0);
          acc[i][j] = __builtin_amdgcn_mfma_f32_16x16x32_bf16(fAl[i], fBh[j], acc[i][j], 0, 0, 0);
        }
    }
  }

  // epilogue: C/D layout col = lane&15, row = (lane>>4)*4 + reg
#pragma unroll
  for (int i = 0; i < 4; ++i) {
#pragma unroll
    for (int j = 0; j < 4; ++j) {
      int col = bn + wc * 64 + j * 16 + (l & 15);
      float bv = bias ? bias[col] : 0.0f;
#pragma unroll
      for (int r = 0; r < 4; ++r) {
        int row = bm + wr * 64 + i * 16 + (l >> 4) * 4 + r;
        if (row < M) {
          float t = acc[i][j][r] + bv;
          if (relu) t = fmaxf(t, 0.0f);
          size_t o = (size_t)row * ldout + col;
          if (outf) outf[o] = t;
          if (outh) {
            ushort h = f2bf(t);
            outh[o] = h;
            outl[o] = f2bf(t - bf2f(h));
          }
        }
      }
    }
  }
}

// ---------------- edge decoder: one wave per edge ----------------

__global__ __launch_bounds__(256) void decode_kernel(const float* __restrict__ AB,
                                                     const int* __restrict__ eli,
                                                     const float* __restrict__ expw,
                                                     const float* __restrict__ wrow,
                                                     const float* __restrict__ bd1,
                                                     const float* __restrict__ Wd2,
                                                     const float* __restrict__ bd2,
                                                     float* __restrict__ out, int E) {
  int wid = blockIdx.x * 4 + (threadIdx.x >> 6);
  int j = threadIdx.x & 63;
  if (wid >= E) return;
  int s = eli[wid];
  int d = eli[E + wid];
  float v = AB[(size_t)s * 128 + j] + AB[(size_t)d * 128 + 64 + j] +
            expw[wid] * wrow[j] + bd1[j];
  float h = fmaxf(v, 0.0f);
  float p = h * Wd2[j];
#pragma unroll
  for (int off = 32; off >= 1; off >>= 1) p += __shfl_xor(p, off);
  if (j == 0) out[wid] = p + bd2[0];
}

// ---------------- launcher ----------------

extern "C" void kernel_launch(void* const* d_in, const int* in_sizes, int n_in,
                              void* d_out, int out_size, void* d_ws, size_t ws_size,
                              hipStream_t stream) {
  const float* x    = (const float*)d_in[0];
  const float* ew   = (const float*)d_in[1];
  const float* expw = (const float*)d_in[2];
  const float* W1r  = (const float*)d_in[3];
  const float* b1   = (const float*)d_in[4];
  const float* W1o  = (const float*)d_in[5];
  const float* W2r  = (const float*)d_in[6];
  const float* b2   = (const float*)d_in[7];
  const float* W2o  = (const float*)d_in[8];
  const float* Wd1  = (const float*)d_in[9];
  const float* bd1  = (const float*)d_in[10];
  const float* Wd2  = (const float*)d_in[11];
  const float* bd2  = (const float*)d_in[12];
  const int* ei     = (const int*)d_in[13];
  const int* eli    = (const int*)d_in[14];
  float* out = (float*)d_out;

  char* ws = (char*)d_ws;
  int* deg      = (int*)(ws + 0);
  int* rowptr   = (int*)(ws + 40064);
  int* cursor   = (int*)(ws + 80128);
  int* s_src    = (int*)(ws + 120192);
  float* s_ew   = (float*)(ws + 760192);
  ushort* x_h   = (ushort*)(ws + 1400192);   // reused as z2_h after gemm1
  ushort* x_l   = (ushort*)(ws + 11640192);  // reused as z2_l
  ushort* agg_h = (ushort*)(ws + 21880192);  // reused as AB (f32) after gemm2
  ushort* agg_l = (ushort*)(ws + 32120192);
  ushort* z1_h  = (ushort*)(ws + 42360192);
  ushort* z1_l  = (ushort*)(ws + 52600192);
  ushort* w1r_th = (ushort*)(ws + 62840192);
  ushort* w1r_tl = (ushort*)(ws + 63364480);
  ushort* w1o_th = (ushort*)(ws + 63888768);
  ushort* w1o_tl = (ushort*)(ws + 64413056);
  ushort* w2r_th = (ushort*)(ws + 64937344);
  ushort* w2r_tl = (ushort*)(ws + 65461632);
  ushort* w2o_th = (ushort*)(ws + 65985920);
  ushort* w2o_tl = (ushort*)(ws + 66510208);
  ushort* bd_th  = (ushort*)(ws + 67034496);
  ushort* bd_tl  = (ushort*)(ws + 67165568);
  ushort* z2_h = x_h;
  ushort* z2_l = x_l;
  float* AB = (float*)agg_h;

  const int* src = ei;
  const int* dst = ei + NE;

  hipMemsetAsync(deg, 0, 40000, stream);
  hist_kernel<<<625, 256, 0, stream>>>(dst, deg, NE);
  scan_kernel<<<1, 256, 0, stream>>>(deg, rowptr, cursor);
  scatter_kernel<<<625, 256, 0, stream>>>(src, dst, ew, cursor, s_src, s_ew, NE);

  // conversions
  split_f32<<<5000, 256, 0, stream>>>(x, x_h, x_l, N_NODES * DIM / 4);
  wtrans<<<dim3(64, 4), 256, 0, stream>>>(W1r, W1o, W2r, W2o, w1r_th, w1r_tl, w1o_th,
                                          w1o_tl, w2r_th, w2r_tl, w2o_th, w2o_tl);
  wd1_build<<<256, 256, 0, stream>>>(Wd1, bd_th, bd_tl);

  // layer 1
  aggregate_split<<<2500, 256, 0, stream>>>(x, nullptr, nullptr, rowptr, s_src, s_ew,
                                            agg_h, agg_l);
  gemm_mfma<<<dim3(79, 4), 256, 0, stream>>>(agg_h, agg_l, w1r_th, w1r_tl, x_h, x_l,
                                             w1o_th, w1o_tl, b1, nullptr, z1_h, z1_l,
                                             N_NODES, DIM, 1);

  // layer 2
  aggregate_split<<<2500, 256, 0, stream>>>(nullptr, z1_h, z1_l, rowptr, s_src, s_ew,
                                            agg_h, agg_l);
  gemm_mfma<<<dim3(79, 4), 256, 0, stream>>>(agg_h, agg_l, w2r_th, w2r_tl, z1_h, z1_l,
                                             w2o_th, w2o_tl, b2, nullptr, z2_h, z2_l,
                                             N_NODES, DIM, 0);

  // decoder node-side precompute: AB = z2 @ [Wd1a | Wd1b]  (M=10000, K=512, N=128)
  gemm_mfma<<<dim3(79, 1), 256, 0, stream>>>(z2_h, z2_l, bd_th, bd_tl, nullptr, nullptr,
                                             nullptr, nullptr, nullptr, AB, nullptr,
                                             nullptr, N_NODES, 128, 0);

  // per-edge decode
  decode_kernel<<<40000, 256, 0, stream>>>(AB, eli, expw, Wd1 + 1024 * 64, bd1, Wd2, bd2,
                                           out, NE);
}

// Round 3
// 253.101 us; speedup vs baseline: 2.1464x; 1.3849x over previous
//
#include <hip/hip_runtime.h>

#define N_NODES 10000
#define DIM 512
#define NE 160000

typedef _Float16 f16;
typedef _Float16 f16x8 __attribute__((ext_vector_type(8)));
typedef float f32x4 __attribute__((ext_vector_type(4)));

__device__ __forceinline__ void gload16(const void* g, void* l) {
  __builtin_amdgcn_global_load_lds((const __attribute__((address_space(1))) void*)g,
                                   (__attribute__((address_space(3))) void*)l, 16, 0, 0);
}

// ---------------- CSR construction ----------------

__global__ __launch_bounds__(256) void hist_kernel(const int* __restrict__ dst,
                                                   int* __restrict__ deg, int E) {
  int e = blockIdx.x * 256 + threadIdx.x;
  if (e < E) atomicAdd(&deg[dst[e]], 1);
}

__global__ __launch_bounds__(256) void scan_kernel(const int* __restrict__ deg,
                                                   int* __restrict__ rowptr,
                                                   int* __restrict__ cursor) {
  __shared__ int partial[256];
  const int CH = 40;
  int tid = threadIdx.x;
  int start = tid * CH;
  int sum = 0;
  for (int i = 0; i < CH; ++i) {
    int idx = start + i;
    if (idx < N_NODES) sum += deg[idx];
  }
  partial[tid] = sum;
  __syncthreads();
  if (tid == 0) {
    int run = 0;
    for (int i = 0; i < 256; ++i) { int t = partial[i]; partial[i] = run; run += t; }
  }
  __syncthreads();
  int off = partial[tid];
  for (int i = 0; i < CH; ++i) {
    int idx = start + i;
    if (idx < N_NODES) {
      rowptr[idx] = off;
      cursor[idx] = off;
      off += deg[idx];
    }
  }
  if (tid == 255) rowptr[N_NODES] = off;
}

__global__ __launch_bounds__(256) void scatter_kernel(const int* __restrict__ src,
                                                      const int* __restrict__ dst,
                                                      const float* __restrict__ ew,
                                                      int* __restrict__ cursor,
                                                      int* __restrict__ s_src,
                                                      float* __restrict__ s_ew, int E) {
  int e = blockIdx.x * 256 + threadIdx.x;
  if (e < E) {
    int d = dst[e];
    int p = atomicAdd(&cursor[d], 1);
    s_src[p] = src[e];
    s_ew[p] = ew[e];
  }
}

// ---------------- conversion kernels ----------------

// split f32 -> (hi,lo) fp16, 4 elems/thread
__global__ __launch_bounds__(256) void split_f32(const float* __restrict__ src,
                                                 f16* __restrict__ hi,
                                                 f16* __restrict__ lo, int n4) {
  int i = blockIdx.x * 256 + threadIdx.x;
  if (i >= n4) return;
  float4 v = ((const float4*)src)[i];
  f16 h0 = (f16)v.x, h1 = (f16)v.y, h2 = (f16)v.z, h3 = (f16)v.w;
  f16 l0 = (f16)(v.x - (float)h0);
  f16 l1 = (f16)(v.y - (float)h1);
  f16 l2 = (f16)(v.z - (float)h2);
  f16 l3 = (f16)(v.w - (float)h3);
  ushort4 hv = {*(ushort*)&h0, *(ushort*)&h1, *(ushort*)&h2, *(ushort*)&h3};
  ushort4 lv = {*(ushort*)&l0, *(ushort*)&l1, *(ushort*)&l2, *(ushort*)&l3};
  ((ushort4*)hi)[i] = hv;
  ((ushort4*)lo)[i] = lv;
}

// transpose 512x512 f32 -> [N][K] single fp16, 4 matrices selected by blockIdx.y
__global__ __launch_bounds__(256) void wtrans(const float* s0, const float* s1,
                                              const float* s2, const float* s3,
                                              f16* d0, f16* d1, f16* d2, f16* d3) {
  const float* src; f16* dh;
  switch (blockIdx.y) {
    case 0: src = s0; dh = d0; break;
    case 1: src = s1; dh = d1; break;
    case 2: src = s2; dh = d2; break;
    default: src = s3; dh = d3; break;
  }
  __shared__ float sT[64][65];
  int tile = blockIdx.x;
  int tr = tile >> 3, tc = tile & 7;
  int tid = threadIdx.x;
  for (int i = 0; i < 16; ++i) {
    int lin = i * 256 + tid;
    int r = lin >> 6, c = lin & 63;
    sT[r][c] = src[(size_t)(tr * 64 + r) * 512 + tc * 64 + c];
  }
  __syncthreads();
  for (int i = 0; i < 16; ++i) {
    int lin = i * 256 + tid;
    int n = lin >> 6, k = lin & 63;
    dh[(size_t)(tc * 64 + n) * 512 + tr * 64 + k] = (f16)sT[k][n];
  }
}

// combined decoder weight, transposed: Bt[j][k]: j<64 -> Wd1[k][j], j>=64 -> Wd1[512+k][j-64]
__global__ __launch_bounds__(256) void wd1_build(const float* __restrict__ Wd1,
                                                 f16* __restrict__ bt) {
  int lin = blockIdx.x * 256 + threadIdx.x;
  if (lin >= 128 * 512) return;
  int j = lin >> 9, k = lin & 511;
  bt[lin] = (f16)Wd1[(size_t)(j < 64 ? k : 512 + k) * 64 + (j & 63)];
}

// ---------------- mean aggregation: one wave per node ----------------
// reads hi fp16 plane only; writes hi/lo fp16

__global__ __launch_bounds__(256) void aggregate_f16(const f16* __restrict__ srch,
                                                     const int* __restrict__ rowptr,
                                                     const int* __restrict__ s_src,
                                                     const float* __restrict__ s_ew,
                                                     f16* __restrict__ aggh,
                                                     f16* __restrict__ aggl) {
  int wid = (blockIdx.x * blockDim.x + threadIdx.x) >> 6;
  int lane = threadIdx.x & 63;
  if (wid >= N_NODES) return;
  int beg = rowptr[wid], end = rowptr[wid + 1];
  float a[8] = {0, 0, 0, 0, 0, 0, 0, 0};
  for (int k = beg; k < end; ++k) {
    int s = s_src[k];
    float wgt = s_ew[k];
    f16x8 v = *(const f16x8*)(srch + (size_t)s * DIM + lane * 8);
#pragma unroll
    for (int t = 0; t < 8; ++t) a[t] += (float)v[t] * wgt;
  }
  float inv = 1.0f / fmaxf((float)(end - beg), 1.0f);
  f16x8 h, l;
#pragma unroll
  for (int t = 0; t < 8; ++t) {
    float o = a[t] * inv;
    f16 hh = (f16)o;
    h[t] = hh;
    l[t] = (f16)(o - (float)hh);
  }
  *(f16x8*)(aggh + (size_t)wid * DIM + lane * 8) = h;
  *(f16x8*)(aggl + (size_t)wid * DIM + lane * 8) = l;
}

// ---------------- MFMA GEMM: out = sum_seg (A_seg @ B_seg^T) ----------------
// A: [M][512] fp16 hi/lo. B: [N][512] fp16 (pre-transposed). 2 MFMA per frag pair.
// Block tile 64 x BN, 4 waves as 2x2, wave tile 32 x (BN/2), BK=32, K=512.

template <int BN>
__global__ __launch_bounds__(256) void gemm_mfma(
    const f16* __restrict__ A1h, const f16* __restrict__ A1l, const f16* __restrict__ B1,
    const f16* __restrict__ A2h, const f16* __restrict__ A2l, const f16* __restrict__ B2,
    const float* __restrict__ bias, float* __restrict__ outf,
    f16* __restrict__ outh, f16* __restrict__ outl,
    int M, int ldout, int relu) {
  constexpr int SLOTS = 8 + BN / 16;   // 1KB slots per K-step
  constexpr int SPW = SLOTS / 4;       // slots per wave
  constexpr int NJ = BN / 32;          // col frags per wave
  __shared__ char smem[(128 + BN) * 64];

  int tid = threadIdx.x;
  int w = tid >> 6, l = tid & 63;
  int bm = blockIdx.x * 64, bn = blockIdx.y * BN;
  int wr = w & 1, wc = w >> 1;

  f32x4 acc[2][NJ] = {};

  int lr = l >> 2;        // row within 16-row slot
  int lc = (l & 3) * 8;   // fp16 col offset within 32-wide stripe

  for (int seg = 0; seg < 2; ++seg) {
    const f16* Ah = seg ? A2h : A1h;
    const f16* Al = seg ? A2l : A1l;
    const f16* B  = seg ? B2 : B1;
    if (!Ah) break;
    for (int k0 = 0; k0 < 512; k0 += 32) {
      __syncthreads();
#pragma unroll
      for (int i = 0; i < SPW; ++i) {
        int s = w * SPW + i;
        const f16* src;
        int grow;
        if (s < 4) {
          src = Ah; grow = bm + s * 16 + lr; if (grow > M - 1) grow = M - 1;
        } else if (s < 8) {
          src = Al; grow = bm + (s - 4) * 16 + lr; if (grow > M - 1) grow = M - 1;
        } else {
          src = B;  grow = bn + (s - 8) * 16 + lr;
        }
        gload16(src + (size_t)grow * 512 + k0 + lc, smem + s * 1024);
      }
      __syncthreads();

      int rsel = l & 15;
      int ksb = (l >> 4) * 16;  // byte offset of k-slice
      f16x8 fAh[2], fAl[2], fB[NJ];
#pragma unroll
      for (int i = 0; i < 2; ++i) {
        int row = wr * 32 + i * 16 + rsel;
        fAh[i] = *(const f16x8*)(smem + row * 64 + ksb);
        fAl[i] = *(const f16x8*)(smem + 4096 + row * 64 + ksb);
      }
#pragma unroll
      for (int j = 0; j < NJ; ++j) {
        int row = wc * (BN / 2) + j * 16 + rsel;
        fB[j] = *(const f16x8*)(smem + 8192 + row * 64 + ksb);
      }
#pragma unroll
      for (int i = 0; i < 2; ++i)
#pragma unroll
        for (int j = 0; j < NJ; ++j) {
          acc[i][j] = __builtin_amdgcn_mfma_f32_16x16x32_f16(fAh[i], fB[j], acc[i][j], 0, 0, 0);
          acc[i][j] = __builtin_amdgcn_mfma_f32_16x16x32_f16(fAl[i], fB[j], acc[i][j], 0, 0, 0);
        }
    }
  }

  // epilogue: C/D layout col = lane&15, row = (lane>>4)*4 + reg
#pragma unroll
  for (int i = 0; i < 2; ++i) {
#pragma unroll
    for (int j = 0; j < NJ; ++j) {
      int col = bn + wc * (BN / 2) + j * 16 + (l & 15);
      float bv = bias ? bias[col] : 0.0f;
#pragma unroll
      for (int r = 0; r < 4; ++r) {
        int row = bm + wr * 32 + i * 16 + (l >> 4) * 4 + r;
        if (row < M) {
          float t = acc[i][j][r] + bv;
          if (relu) t = fmaxf(t, 0.0f);
          size_t o = (size_t)row * ldout + col;
          if (outf) outf[o] = t;
          if (outh) {
            f16 hh = (f16)t;
            outh[o] = hh;
            outl[o] = (f16)(t - (float)hh);
          }
        }
      }
    }
  }
}

// ---------------- edge decoder: one wave per edge ----------------

__global__ __launch_bounds__(256) void decode_kernel(const float* __restrict__ AB,
                                                     const int* __restrict__ eli,
                                                     const float* __restrict__ expw,
                                                     const float* __restrict__ wrow,
                                                     const float* __restrict__ bd1,
                                                     const float* __restrict__ Wd2,
                                                     const float* __restrict__ bd2,
                                                     float* __restrict__ out, int E) {
  int wid = blockIdx.x * 4 + (threadIdx.x >> 6);
  int j = threadIdx.x & 63;
  if (wid >= E) return;
  int s = eli[wid];
  int d = eli[E + wid];
  float v = AB[(size_t)s * 128 + j] + AB[(size_t)d * 128 + 64 + j] +
            expw[wid] * wrow[j] + bd1[j];
  float h = fmaxf(v, 0.0f);
  float p = h * Wd2[j];
#pragma unroll
  for (int off = 32; off >= 1; off >>= 1) p += __shfl_xor(p, off);
  if (j == 0) out[wid] = p + bd2[0];
}

// ---------------- launcher ----------------

extern "C" void kernel_launch(void* const* d_in, const int* in_sizes, int n_in,
                              void* d_out, int out_size, void* d_ws, size_t ws_size,
                              hipStream_t stream) {
  const float* x    = (const float*)d_in[0];
  const float* ew   = (const float*)d_in[1];
  const float* expw = (const float*)d_in[2];
  const float* W1r  = (const float*)d_in[3];
  const float* b1   = (const float*)d_in[4];
  const float* W1o  = (const float*)d_in[5];
  const float* W2r  = (const float*)d_in[6];
  const float* b2   = (const float*)d_in[7];
  const float* W2o  = (const float*)d_in[8];
  const float* Wd1  = (const float*)d_in[9];
  const float* bd1  = (const float*)d_in[10];
  const float* Wd2  = (const float*)d_in[11];
  const float* bd2  = (const float*)d_in[12];
  const int* ei     = (const int*)d_in[13];
  const int* eli    = (const int*)d_in[14];
  float* out = (float*)d_out;

  char* ws = (char*)d_ws;
  int* deg    = (int*)(ws + 0);
  int* rowptr = (int*)(ws + 40064);
  int* cursor = (int*)(ws + 80128);
  int* s_src  = (int*)(ws + 120192);
  float* s_ew = (float*)(ws + 760192);
  f16* x_h    = (f16*)(ws + 1400192);   // 10.24 MB each; reused as z2_h/z2_l
  f16* x_l    = (f16*)(ws + 11640192);
  f16* agg_h  = (f16*)(ws + 21880192);  // reused as AB (f32) for decoder
  f16* agg_l  = (f16*)(ws + 32120192);
  f16* z1_h   = (f16*)(ws + 42360192);
  f16* z1_l   = (f16*)(ws + 52600192);
  f16* w1r_t  = (f16*)(ws + 62840192);
  f16* w1o_t  = (f16*)(ws + 63364480);
  f16* w2r_t  = (f16*)(ws + 63888768);
  f16* w2o_t  = (f16*)(ws + 64413056);
  f16* bd_t   = (f16*)(ws + 64937344);
  f16* z2_h = x_h;
  f16* z2_l = x_l;
  float* AB = (float*)agg_h;

  const int* src = ei;
  const int* dst = ei + NE;

  hipMemsetAsync(deg, 0, 40000, stream);
  hist_kernel<<<625, 256, 0, stream>>>(dst, deg, NE);
  scan_kernel<<<1, 256, 0, stream>>>(deg, rowptr, cursor);
  scatter_kernel<<<625, 256, 0, stream>>>(src, dst, ew, cursor, s_src, s_ew, NE);

  // conversions
  split_f32<<<5000, 256, 0, stream>>>(x, x_h, x_l, N_NODES * DIM / 4);
  wtrans<<<dim3(64, 4), 256, 0, stream>>>(W1r, W1o, W2r, W2o, w1r_t, w1o_t, w2r_t, w2o_t);
  wd1_build<<<256, 256, 0, stream>>>(Wd1, bd_t);

  // layer 1: z1 = relu(mean-agg(x) @ W1r + x @ W1o + b1)
  aggregate_f16<<<2500, 256, 0, stream>>>(x_h, rowptr, s_src, s_ew, agg_h, agg_l);
  gemm_mfma<128><<<dim3(157, 4), 256, 0, stream>>>(agg_h, agg_l, w1r_t, x_h, x_l, w1o_t,
                                                   b1, nullptr, z1_h, z1_l, N_NODES, DIM, 1);

  // layer 2: z2 = mean-agg(z1) @ W2r + z1 @ W2o + b2
  aggregate_f16<<<2500, 256, 0, stream>>>(z1_h, rowptr, s_src, s_ew, agg_h, agg_l);
  gemm_mfma<128><<<dim3(157, 4), 256, 0, stream>>>(agg_h, agg_l, w2r_t, z1_h, z1_l, w2o_t,
                                                   b2, nullptr, z2_h, z2_l, N_NODES, DIM, 0);

  // decoder node-side precompute: AB = z2 @ [Wd1a | Wd1b]  (M=10000, K=512, N=128)
  gemm_mfma<64><<<dim3(157, 2), 256, 0, stream>>>(z2_h, z2_l, bd_t, nullptr, nullptr,
                                                  nullptr, nullptr, AB, nullptr, nullptr,
                                                  N_NODES, 128, 0);

  // per-edge decode
  decode_kernel<<<40000, 256, 0, stream>>>(AB, eli, expw, Wd1 + 1024 * 64, bd1, Wd2, bd2,
                                           out, NE);
}

// Round 4
// 210.340 us; speedup vs baseline: 2.5828x; 1.2033x over previous
//
#include <hip/hip_runtime.h>

#define N_NODES 10000
#define DIM 512
#define NE 160000

typedef _Float16 f16;
typedef _Float16 f16x8 __attribute__((ext_vector_type(8)));
typedef float f32x4 __attribute__((ext_vector_type(4)));

__device__ __forceinline__ void gload16(const void* g, void* l) {
  __builtin_amdgcn_global_load_lds((const __attribute__((address_space(1))) void*)g,
                                   (__attribute__((address_space(3))) void*)l, 16, 0, 0);
}

// ---------------- CSR construction ----------------

__global__ __launch_bounds__(256) void hist_kernel(const int* __restrict__ dst,
                                                   int* __restrict__ deg, int E) {
  int e = blockIdx.x * 256 + threadIdx.x;
  if (e < E) atomicAdd(&deg[dst[e]], 1);
}

__global__ __launch_bounds__(256) void scan_kernel(const int* __restrict__ deg,
                                                   int* __restrict__ rowptr,
                                                   int* __restrict__ cursor) {
  __shared__ int partial[256];
  const int CH = 40;
  int tid = threadIdx.x;
  int start = tid * CH;
  int sum = 0;
  for (int i = 0; i < CH; ++i) {
    int idx = start + i;
    if (idx < N_NODES) sum += deg[idx];
  }
  partial[tid] = sum;
  __syncthreads();
  if (tid == 0) {
    int run = 0;
    for (int i = 0; i < 256; ++i) { int t = partial[i]; partial[i] = run; run += t; }
  }
  __syncthreads();
  int off = partial[tid];
  for (int i = 0; i < CH; ++i) {
    int idx = start + i;
    if (idx < N_NODES) {
      rowptr[idx] = off;
      cursor[idx] = off;
      off += deg[idx];
    }
  }
  if (tid == 255) rowptr[N_NODES] = off;
}

__global__ __launch_bounds__(256) void scatter_kernel(const int* __restrict__ src,
                                                      const int* __restrict__ dst,
                                                      const float* __restrict__ ew,
                                                      int* __restrict__ cursor,
                                                      int* __restrict__ s_src,
                                                      float* __restrict__ s_ew, int E) {
  int e = blockIdx.x * 256 + threadIdx.x;
  if (e < E) {
    int d = dst[e];
    int p = atomicAdd(&cursor[d], 1);
    s_src[p] = src[e];
    s_ew[p] = ew[e];
  }
}

// ---------------- conversion kernels ----------------

__global__ __launch_bounds__(256) void cast_f16(const float* __restrict__ src,
                                                f16* __restrict__ dst, int n4) {
  int i = blockIdx.x * 256 + threadIdx.x;
  if (i >= n4) return;
  float4 v = ((const float4*)src)[i];
  f16 h0 = (f16)v.x, h1 = (f16)v.y, h2 = (f16)v.z, h3 = (f16)v.w;
  ushort4 hv = {*(ushort*)&h0, *(ushort*)&h1, *(ushort*)&h2, *(ushort*)&h3};
  ((ushort4*)dst)[i] = hv;
}

// transpose 512x512 f32 -> [N][K] fp16, 4 matrices selected by blockIdx.y
__global__ __launch_bounds__(256) void wtrans(const float* s0, const float* s1,
                                              const float* s2, const float* s3,
                                              f16* d0, f16* d1, f16* d2, f16* d3) {
  const float* src; f16* dh;
  switch (blockIdx.y) {
    case 0: src = s0; dh = d0; break;
    case 1: src = s1; dh = d1; break;
    case 2: src = s2; dh = d2; break;
    default: src = s3; dh = d3; break;
  }
  __shared__ float sT[64][65];
  int tile = blockIdx.x;
  int tr = tile >> 3, tc = tile & 7;
  int tid = threadIdx.x;
  for (int i = 0; i < 16; ++i) {
    int lin = i * 256 + tid;
    int r = lin >> 6, c = lin & 63;
    sT[r][c] = src[(size_t)(tr * 64 + r) * 512 + tc * 64 + c];
  }
  __syncthreads();
  for (int i = 0; i < 16; ++i) {
    int lin = i * 256 + tid;
    int n = lin >> 6, k = lin & 63;
    dh[(size_t)(tc * 64 + n) * 512 + tr * 64 + k] = (f16)sT[k][n];
  }
}

// combined decoder weight, transposed: Bt[j][k]: j<64 -> Wd1[k][j], j>=64 -> Wd1[512+k][j-64]
__global__ __launch_bounds__(256) void wd1_build(const float* __restrict__ Wd1,
                                                 f16* __restrict__ bt) {
  int lin = blockIdx.x * 256 + threadIdx.x;
  if (lin >= 128 * 512) return;
  int j = lin >> 9, k = lin & 511;
  bt[lin] = (f16)Wd1[(size_t)(j < 64 ? k : 512 + k) * 64 + (j & 63)];
}

// ---------------- MFMA GEMM: out(f16) = A(f16) @ B(f16)^T ----------------
// A: [M][512]. B: [NB*BN][512] pre-transposed. Block tile 64 x BN, 4 waves 2x2,
// wave tile 32 x BN/2, BK=32, K=512. XCD-chunked bijective block swizzle (T1/m204).

template <int BN>
__global__ __launch_bounds__(256) void gemm_f16(const f16* __restrict__ A,
                                                const f16* __restrict__ B,
                                                f16* __restrict__ out, int M, int NB,
                                                int ldout) {
  constexpr int SLOTS = 4 + BN / 16;
  constexpr int SPW = SLOTS / 4;
  constexpr int NJ = BN / 32;
  __shared__ char smem[SLOTS * 1024];

  // bijective XCD swizzle: consecutive swz share an XCD and share bm (bn fastest)
  int n = gridDim.x;
  int lin = blockIdx.x;
  int q = n >> 3, r = n & 7, xcd = lin & 7;
  int base = xcd < r ? xcd * (q + 1) : r * (q + 1) + (xcd - r) * q;
  int swz = base + (lin >> 3);
  int bm = (swz / NB) * 64;
  int bn = (swz % NB) * BN;

  int tid = threadIdx.x;
  int w = tid >> 6, l = tid & 63;
  int wr = w & 1, wc = w >> 1;

  f32x4 acc[2][NJ] = {};

  int lr = l >> 2;        // row within 16-row slot
  int lc = (l & 3) * 8;   // fp16 offset within 32-wide stripe

  for (int k0 = 0; k0 < 512; k0 += 32) {
    __syncthreads();
#pragma unroll
    for (int i = 0; i < SPW; ++i) {
      int s = w * SPW + i;
      const f16* src;
      int grow;
      if (s < 4) {
        src = A; grow = bm + s * 16 + lr; if (grow > M - 1) grow = M - 1;
      } else {
        src = B; grow = bn + (s - 4) * 16 + lr;
      }
      gload16(src + (size_t)grow * 512 + k0 + lc, smem + s * 1024);
    }
    __syncthreads();

    int rsel = l & 15;
    int ksb = (l >> 4) * 16;  // byte offset of k-slice
    f16x8 fA[2], fB[NJ];
#pragma unroll
    for (int i = 0; i < 2; ++i)
      fA[i] = *(const f16x8*)(smem + (wr * 2 + i) * 1024 + rsel * 64 + ksb);
#pragma unroll
    for (int j = 0; j < NJ; ++j)
      fB[j] = *(const f16x8*)(smem + (4 + wc * NJ + j) * 1024 + rsel * 64 + ksb);
#pragma unroll
    for (int i = 0; i < 2; ++i)
#pragma unroll
      for (int j = 0; j < NJ; ++j)
        acc[i][j] = __builtin_amdgcn_mfma_f32_16x16x32_f16(fA[i], fB[j], acc[i][j], 0, 0, 0);
  }

  // epilogue: C/D layout col = lane&15, row = (lane>>4)*4 + reg
#pragma unroll
  for (int i = 0; i < 2; ++i) {
#pragma unroll
    for (int j = 0; j < NJ; ++j) {
      int col = bn + wc * (BN / 2) + j * 16 + (l & 15);
#pragma unroll
      for (int rg = 0; rg < 4; ++rg) {
        int row = bm + wr * 32 + i * 16 + (l >> 4) * 4 + rg;
        if (row < M) out[(size_t)row * ldout + col] = (f16)acc[i][j][rg];
      }
    }
  }
}

// ---------------- combine: z = [relu](mean-gather(Y_left) + Y_right + bias) --------
// Y: [N][1024] fp16 (left 512 = rel-GEMM result, right 512 = root-GEMM result)

__global__ __launch_bounds__(256) void combine(const f16* __restrict__ Y,
                                               const int* __restrict__ rowptr,
                                               const int* __restrict__ s_src,
                                               const float* __restrict__ s_ew,
                                               const float* __restrict__ bias,
                                               f16* __restrict__ z, int relu) {
  int wid = (blockIdx.x * blockDim.x + threadIdx.x) >> 6;
  int lane = threadIdx.x & 63;
  if (wid >= N_NODES) return;
  int beg = rowptr[wid], end = rowptr[wid + 1];
  float a[8] = {0, 0, 0, 0, 0, 0, 0, 0};
  for (int k = beg; k < end; ++k) {
    int s = s_src[k];
    float wgt = s_ew[k];
    f16x8 v = *(const f16x8*)(Y + (size_t)s * 1024 + lane * 8);
#pragma unroll
    for (int t = 0; t < 8; ++t) a[t] += (float)v[t] * wgt;
  }
  float inv = 1.0f / fmaxf((float)(end - beg), 1.0f);
  f16x8 rt = *(const f16x8*)(Y + (size_t)wid * 1024 + 512 + lane * 8);
  float4 b0 = *(const float4*)(bias + lane * 8);
  float4 b1v = *(const float4*)(bias + lane * 8 + 4);
  float bb[8] = {b0.x, b0.y, b0.z, b0.w, b1v.x, b1v.y, b1v.z, b1v.w};
  f16x8 o;
#pragma unroll
  for (int t = 0; t < 8; ++t) {
    float v = a[t] * inv + (float)rt[t] + bb[t];
    if (relu) v = fmaxf(v, 0.0f);
    o[t] = (f16)v;
  }
  *(f16x8*)(z + (size_t)wid * DIM + lane * 8) = o;
}

// ---------------- edge decoder: one wave per edge, fp16 AB ----------------

__global__ __launch_bounds__(256) void decode_kernel(const f16* __restrict__ AB,
                                                     const int* __restrict__ eli,
                                                     const float* __restrict__ expw,
                                                     const float* __restrict__ wrow,
                                                     const float* __restrict__ bd1,
                                                     const float* __restrict__ Wd2,
                                                     const float* __restrict__ bd2,
                                                     float* __restrict__ out, int E) {
  int wid = blockIdx.x * 4 + (threadIdx.x >> 6);
  int j = threadIdx.x & 63;
  if (wid >= E) return;
  int s = eli[wid];
  int d = eli[E + wid];
  float v = (float)AB[(size_t)s * 128 + j] + (float)AB[(size_t)d * 128 + 64 + j] +
            expw[wid] * wrow[j] + bd1[j];
  float h = fmaxf(v, 0.0f);
  float p = h * Wd2[j];
#pragma unroll
  for (int off = 32; off >= 1; off >>= 1) p += __shfl_xor(p, off);
  if (j == 0) out[wid] = p + bd2[0];
}

// ---------------- launcher ----------------

extern "C" void kernel_launch(void* const* d_in, const int* in_sizes, int n_in,
                              void* d_out, int out_size, void* d_ws, size_t ws_size,
                              hipStream_t stream) {
  const float* x    = (const float*)d_in[0];
  const float* ew   = (const float*)d_in[1];
  const float* expw = (const float*)d_in[2];
  const float* W1r  = (const float*)d_in[3];
  const float* b1   = (const float*)d_in[4];
  const float* W1o  = (const float*)d_in[5];
  const float* W2r  = (const float*)d_in[6];
  const float* b2   = (const float*)d_in[7];
  const float* W2o  = (const float*)d_in[8];
  const float* Wd1  = (const float*)d_in[9];
  const float* bd1  = (const float*)d_in[10];
  const float* Wd2  = (const float*)d_in[11];
  const float* bd2  = (const float*)d_in[12];
  const int* ei     = (const int*)d_in[13];
  const int* eli    = (const int*)d_in[14];
  float* out = (float*)d_out;

  char* ws = (char*)d_ws;
  int* deg    = (int*)(ws + 0);
  int* rowptr = (int*)(ws + 40064);
  int* cursor = (int*)(ws + 80128);
  int* s_src  = (int*)(ws + 120192);
  float* s_ew = (float*)(ws + 760192);
  f16* x16    = (f16*)(ws + 1400192);   // 10.24 MB
  f16* z1     = (f16*)(ws + 11640192);  // 10.24 MB
  f16* z2     = (f16*)(ws + 21880192);  // 10.24 MB
  f16* Y      = (f16*)(ws + 32120192);  // 20.48 MB
  f16* AB16   = (f16*)(ws + 52600192);  // 2.56 MB
  f16* w1c    = (f16*)(ws + 55160192);  // 1 MB  [1024][512]
  f16* w2c    = (f16*)(ws + 56208768);  // 1 MB
  f16* bdt    = (f16*)(ws + 57257344);  // 128 KB [128][512]

  const int* src = ei;
  const int* dst = ei + NE;

  hipMemsetAsync(deg, 0, 40000, stream);
  hist_kernel<<<625, 256, 0, stream>>>(dst, deg, NE);
  scan_kernel<<<1, 256, 0, stream>>>(deg, rowptr, cursor);
  scatter_kernel<<<625, 256, 0, stream>>>(src, dst, ew, cursor, s_src, s_ew, NE);

  // conversions
  cast_f16<<<5000, 256, 0, stream>>>(x, x16, N_NODES * DIM / 4);
  wtrans<<<dim3(64, 4), 256, 0, stream>>>(W1r, W1o, W2r, W2o, w1c, w1c + 512 * 512,
                                          w2c, w2c + 512 * 512);
  wd1_build<<<256, 256, 0, stream>>>(Wd1, bdt);

  // layer 1: Y = x @ [W1r | W1o]; z1 = relu(mean-agg(Y_l) + Y_r + b1)
  gemm_f16<128><<<157 * 8, 256, 0, stream>>>(x16, w1c, Y, N_NODES, 8, 1024);
  combine<<<2500, 256, 0, stream>>>(Y, rowptr, s_src, s_ew, b1, z1, 1);

  // layer 2: Y = z1 @ [W2r | W2o]; z2 = mean-agg(Y_l) + Y_r + b2
  gemm_f16<128><<<157 * 8, 256, 0, stream>>>(z1, w2c, Y, N_NODES, 8, 1024);
  combine<<<2500, 256, 0, stream>>>(Y, rowptr, s_src, s_ew, b2, z2, 0);

  // decoder node-side precompute: AB = z2 @ [Wd1a | Wd1b]  (M=10000, K=512, N=128)
  gemm_f16<64><<<157 * 2, 256, 0, stream>>>(z2, bdt, AB16, N_NODES, 2, 128);

  // per-edge decode
  decode_kernel<<<40000, 256, 0, stream>>>(AB16, eli, expw, Wd1 + 1024 * 64, bd1, Wd2,
                                           bd2, out, NE);
}

// Round 5
// 188.794 us; speedup vs baseline: 2.8775x; 1.1141x over previous
//
#include <hip/hip_runtime.h>

#define N_NODES 10000
#define DIM 512
#define NE 160000

typedef _Float16 f16;
typedef _Float16 f16x2 __attribute__((ext_vector_type(2)));
typedef _Float16 f16x8 __attribute__((ext_vector_type(8)));
typedef float f32x4 __attribute__((ext_vector_type(4)));

__device__ __forceinline__ void gload16(const void* g, void* l) {
  __builtin_amdgcn_global_load_lds((const __attribute__((address_space(1))) void*)g,
                                   (__attribute__((address_space(3))) void*)l, 16, 0, 0);
}

// ---------------- CSR construction ----------------

__global__ __launch_bounds__(256) void zero_deg(int* __restrict__ deg) {
  int i = blockIdx.x * 256 + threadIdx.x;
  if (i < N_NODES) deg[i] = 0;
}

__global__ __launch_bounds__(256) void hist_kernel(const int* __restrict__ dst,
                                                   int* __restrict__ deg, int E) {
  int e = blockIdx.x * 256 + threadIdx.x;
  if (e < E) atomicAdd(&deg[dst[e]], 1);
}

__global__ __launch_bounds__(256) void scan_kernel(const int* __restrict__ deg,
                                                   int* __restrict__ rowptr,
                                                   int* __restrict__ cursor) {
  __shared__ int partial[256];
  const int CH = 40;
  int tid = threadIdx.x;
  int start = tid * CH;
  int sum = 0;
  for (int i = 0; i < CH; ++i) {
    int idx = start + i;
    if (idx < N_NODES) sum += deg[idx];
  }
  partial[tid] = sum;
  __syncthreads();
  if (tid == 0) {
    int run = 0;
    for (int i = 0; i < 256; ++i) { int t = partial[i]; partial[i] = run; run += t; }
  }
  __syncthreads();
  int off = partial[tid];
  for (int i = 0; i < CH; ++i) {
    int idx = start + i;
    if (idx < N_NODES) {
      rowptr[idx] = off;
      cursor[idx] = off;
      off += deg[idx];
    }
  }
  if (tid == 255) rowptr[N_NODES] = off;
}

__global__ __launch_bounds__(256) void scatter_kernel(const int* __restrict__ src,
                                                      const int* __restrict__ dst,
                                                      const float* __restrict__ ew,
                                                      int* __restrict__ cursor,
                                                      int* __restrict__ s_src,
                                                      float* __restrict__ s_ew, int E) {
  int e = blockIdx.x * 256 + threadIdx.x;
  if (e < E) {
    int d = dst[e];
    int p = atomicAdd(&cursor[d], 1);
    s_src[p] = src[e];
    s_ew[p] = ew[e];
  }
}

// ---------------- conversion kernels ----------------

__global__ __launch_bounds__(256) void cast_f16(const float* __restrict__ src,
                                                f16* __restrict__ dst, int n4) {
  int i = blockIdx.x * 256 + threadIdx.x;
  if (i >= n4) return;
  float4 v = ((const float4*)src)[i];
  f16 h0 = (f16)v.x, h1 = (f16)v.y, h2 = (f16)v.z, h3 = (f16)v.w;
  ushort4 hv = {*(ushort*)&h0, *(ushort*)&h1, *(ushort*)&h2, *(ushort*)&h3};
  ((ushort4*)dst)[i] = hv;
}

// transpose 512x512 f32 -> [N][K] fp16, 4 matrices selected by blockIdx.y
__global__ __launch_bounds__(256) void wtrans(const float* s0, const float* s1,
                                              const float* s2, const float* s3,
                                              f16* d0, f16* d1, f16* d2, f16* d3) {
  const float* src; f16* dh;
  switch (blockIdx.y) {
    case 0: src = s0; dh = d0; break;
    case 1: src = s1; dh = d1; break;
    case 2: src = s2; dh = d2; break;
    default: src = s3; dh = d3; break;
  }
  __shared__ float sT[64][65];
  int tile = blockIdx.x;
  int tr = tile >> 3, tc = tile & 7;
  int tid = threadIdx.x;
  for (int i = 0; i < 16; ++i) {
    int lin = i * 256 + tid;
    int r = lin >> 6, c = lin & 63;
    sT[r][c] = src[(size_t)(tr * 64 + r) * 512 + tc * 64 + c];
  }
  __syncthreads();
  for (int i = 0; i < 16; ++i) {
    int lin = i * 256 + tid;
    int n = lin >> 6, k = lin & 63;
    dh[(size_t)(tc * 64 + n) * 512 + tr * 64 + k] = (f16)sT[k][n];
  }
}

// combined decoder weight, transposed: Bt[j][k]: j<64 -> Wd1[k][j], j>=64 -> Wd1[512+k][j-64]
__global__ __launch_bounds__(256) void wd1_build(const float* __restrict__ Wd1,
                                                 f16* __restrict__ bt) {
  int lin = blockIdx.x * 256 + threadIdx.x;
  if (lin >= 128 * 512) return;
  int j = lin >> 9, k = lin & 511;
  bt[lin] = (f16)Wd1[(size_t)(j < 64 ? k : 512 + k) * 64 + (j & 63)];
}

// ---------------- MFMA GEMM: out(f16) = A(f16) @ B(f16)^T ----------------
// A: [M][512]. B: [NB*BN][512] pre-transposed. Block tile 64 x BN, 4 waves 2x2,
// wave tile 32 x BN/2, BK=32, K=512. XCD-chunked bijective block swizzle (T1/m204).

template <int BN>
__global__ __launch_bounds__(256) void gemm_f16(const f16* __restrict__ A,
                                                const f16* __restrict__ B,
                                                f16* __restrict__ out, int M, int NB,
                                                int ldout) {
  constexpr int SLOTS = 4 + BN / 16;
  constexpr int SPW = SLOTS / 4;
  constexpr int NJ = BN / 32;
  __shared__ char smem[SLOTS * 1024];

  // bijective XCD swizzle: consecutive swz share an XCD and share bm (bn fastest)
  int n = gridDim.x;
  int lin = blockIdx.x;
  int q = n >> 3, r = n & 7, xcd = lin & 7;
  int base = xcd < r ? xcd * (q + 1) : r * (q + 1) + (xcd - r) * q;
  int swz = base + (lin >> 3);
  int bm = (swz / NB) * 64;
  int bn = (swz % NB) * BN;

  int tid = threadIdx.x;
  int w = tid >> 6, l = tid & 63;
  int wr = w & 1, wc = w >> 1;

  f32x4 acc[2][NJ] = {};

  int lr = l >> 2;        // row within 16-row slot
  int lc = (l & 3) * 8;   // fp16 offset within 32-wide stripe

  for (int k0 = 0; k0 < 512; k0 += 32) {
    __syncthreads();
#pragma unroll
    for (int i = 0; i < SPW; ++i) {
      int s = w * SPW + i;
      const f16* src;
      int grow;
      if (s < 4) {
        src = A; grow = bm + s * 16 + lr; if (grow > M - 1) grow = M - 1;
      } else {
        src = B; grow = bn + (s - 4) * 16 + lr;
      }
      gload16(src + (size_t)grow * 512 + k0 + lc, smem + s * 1024);
    }
    __syncthreads();

    int rsel = l & 15;
    int ksb = (l >> 4) * 16;  // byte offset of k-slice
    f16x8 fA[2], fB[NJ];
#pragma unroll
    for (int i = 0; i < 2; ++i)
      fA[i] = *(const f16x8*)(smem + (wr * 2 + i) * 1024 + rsel * 64 + ksb);
#pragma unroll
    for (int j = 0; j < NJ; ++j)
      fB[j] = *(const f16x8*)(smem + (4 + wc * NJ + j) * 1024 + rsel * 64 + ksb);
#pragma unroll
    for (int i = 0; i < 2; ++i)
#pragma unroll
      for (int j = 0; j < NJ; ++j)
        acc[i][j] = __builtin_amdgcn_mfma_f32_16x16x32_f16(fA[i], fB[j], acc[i][j], 0, 0, 0);
  }

  // epilogue: C/D layout col = lane&15, row = (lane>>4)*4 + reg
#pragma unroll
  for (int i = 0; i < 2; ++i) {
#pragma unroll
    for (int j = 0; j < NJ; ++j) {
      int col = bn + wc * (BN / 2) + j * 16 + (l & 15);
#pragma unroll
      for (int rg = 0; rg < 4; ++rg) {
        int row = bm + wr * 32 + i * 16 + (l >> 4) * 4 + rg;
        if (row < M) out[(size_t)row * ldout + col] = (f16)acc[i][j][rg];
      }
    }
  }
}

// ---------------- combine: z = [relu](mean-gather(Y_left) + Y_right + bias) --------
// Y: [N][1024] fp16 (left 512 = rel-GEMM result, right 512 = root-GEMM result)

__global__ __launch_bounds__(256) void combine(const f16* __restrict__ Y,
                                               const int* __restrict__ rowptr,
                                               const int* __restrict__ s_src,
                                               const float* __restrict__ s_ew,
                                               const float* __restrict__ bias,
                                               f16* __restrict__ z, int relu) {
  int wid = (blockIdx.x * blockDim.x + threadIdx.x) >> 6;
  int lane = threadIdx.x & 63;
  if (wid >= N_NODES) return;
  int beg = rowptr[wid], end = rowptr[wid + 1];
  float a0[8] = {0, 0, 0, 0, 0, 0, 0, 0};
  float a1[8] = {0, 0, 0, 0, 0, 0, 0, 0};
  int k = beg;
  for (; k + 1 < end; k += 2) {
    int sA = s_src[k], sB = s_src[k + 1];
    float wA = s_ew[k], wB = s_ew[k + 1];
    f16x8 vA = *(const f16x8*)(Y + (size_t)sA * 1024 + lane * 8);
    f16x8 vB = *(const f16x8*)(Y + (size_t)sB * 1024 + lane * 8);
#pragma unroll
    for (int t = 0; t < 8; ++t) {
      a0[t] += (float)vA[t] * wA;
      a1[t] += (float)vB[t] * wB;
    }
  }
  if (k < end) {
    int sA = s_src[k];
    float wA = s_ew[k];
    f16x8 vA = *(const f16x8*)(Y + (size_t)sA * 1024 + lane * 8);
#pragma unroll
    for (int t = 0; t < 8; ++t) a0[t] += (float)vA[t] * wA;
  }
  float inv = 1.0f / fmaxf((float)(end - beg), 1.0f);
  f16x8 rt = *(const f16x8*)(Y + (size_t)wid * 1024 + 512 + lane * 8);
  float4 b0 = *(const float4*)(bias + lane * 8);
  float4 b1v = *(const float4*)(bias + lane * 8 + 4);
  float bb[8] = {b0.x, b0.y, b0.z, b0.w, b1v.x, b1v.y, b1v.z, b1v.w};
  f16x8 o;
#pragma unroll
  for (int t = 0; t < 8; ++t) {
    float v = (a0[t] + a1[t]) * inv + (float)rt[t] + bb[t];
    if (relu) v = fmaxf(v, 0.0f);
    o[t] = (f16)v;
  }
  *(f16x8*)(z + (size_t)wid * DIM + lane * 8) = o;
}

// ---------------- edge decoder: half-wave (32 lanes) per edge, f16x2 loads --------

__global__ __launch_bounds__(256) void decode_kernel(const f16* __restrict__ AB,
                                                     const int* __restrict__ eli,
                                                     const float* __restrict__ expw,
                                                     const float* __restrict__ wrow,
                                                     const float* __restrict__ bd1,
                                                     const float* __restrict__ Wd2,
                                                     const float* __restrict__ bd2,
                                                     float* __restrict__ out, int E) {
  int wid = blockIdx.x * 8 + (threadIdx.x >> 5);
  int j = threadIdx.x & 31;
  if (wid >= E) return;
  int s = eli[wid];
  int d = eli[E + wid];
  float2 sw = *(const float2*)(wrow + 2 * j);
  float2 sb = *(const float2*)(bd1 + 2 * j);
  float2 s2 = *(const float2*)(Wd2 + 2 * j);
  f16x2 va = *(const f16x2*)(AB + (size_t)s * 128 + 2 * j);
  f16x2 vb = *(const f16x2*)(AB + (size_t)d * 128 + 64 + 2 * j);
  float w = expw[wid];
  float h0 = fmaxf((float)va[0] + (float)vb[0] + w * sw.x + sb.x, 0.0f);
  float h1 = fmaxf((float)va[1] + (float)vb[1] + w * sw.y + sb.y, 0.0f);
  float p = h0 * s2.x + h1 * s2.y;
#pragma unroll
  for (int off = 16; off >= 1; off >>= 1) p += __shfl_xor(p, off);
  if (j == 0) out[wid] = p + bd2[0];
}

// ---------------- launcher ----------------

extern "C" void kernel_launch(void* const* d_in, const int* in_sizes, int n_in,
                              void* d_out, int out_size, void* d_ws, size_t ws_size,
                              hipStream_t stream) {
  const float* x    = (const float*)d_in[0];
  const float* ew   = (const float*)d_in[1];
  const float* expw = (const float*)d_in[2];
  const float* W1r  = (const float*)d_in[3];
  const float* b1   = (const float*)d_in[4];
  const float* W1o  = (const float*)d_in[5];
  const float* W2r  = (const float*)d_in[6];
  const float* b2   = (const float*)d_in[7];
  const float* W2o  = (const float*)d_in[8];
  const float* Wd1  = (const float*)d_in[9];
  const float* bd1  = (const float*)d_in[10];
  const float* Wd2  = (const float*)d_in[11];
  const float* bd2  = (const float*)d_in[12];
  const int* ei     = (const int*)d_in[13];
  const int* eli    = (const int*)d_in[14];
  float* out = (float*)d_out;

  char* ws = (char*)d_ws;
  int* deg    = (int*)(ws + 0);
  int* rowptr = (int*)(ws + 40064);
  int* cursor = (int*)(ws + 80128);
  int* s_src  = (int*)(ws + 120192);
  float* s_ew = (float*)(ws + 760192);
  f16* x16    = (f16*)(ws + 1400192);   // 10.24 MB
  f16* z1     = (f16*)(ws + 11640192);  // 10.24 MB
  f16* z2     = (f16*)(ws + 21880192);  // 10.24 MB
  f16* Y      = (f16*)(ws + 32120192);  // 20.48 MB
  f16* AB16   = (f16*)(ws + 52600192);  // 2.56 MB
  f16* w1c    = (f16*)(ws + 55160192);  // 1 MB  [1024][512]
  f16* w2c    = (f16*)(ws + 56208768);  // 1 MB
  f16* bdt    = (f16*)(ws + 57257344);  // 128 KB [128][512]

  const int* src = ei;
  const int* dst = ei + NE;

  zero_deg<<<40, 256, 0, stream>>>(deg);
  hist_kernel<<<625, 256, 0, stream>>>(dst, deg, NE);
  scan_kernel<<<1, 256, 0, stream>>>(deg, rowptr, cursor);
  scatter_kernel<<<625, 256, 0, stream>>>(src, dst, ew, cursor, s_src, s_ew, NE);

  // conversions
  cast_f16<<<5000, 256, 0, stream>>>(x, x16, N_NODES * DIM / 4);
  wtrans<<<dim3(64, 4), 256, 0, stream>>>(W1r, W1o, W2r, W2o, w1c, w1c + 512 * 512,
                                          w2c, w2c + 512 * 512);
  wd1_build<<<256, 256, 0, stream>>>(Wd1, bdt);

  // layer 1: Y = x @ [W1r | W1o]; z1 = relu(mean-agg(Y_l) + Y_r + b1)
  gemm_f16<128><<<157 * 8, 256, 0, stream>>>(x16, w1c, Y, N_NODES, 8, 1024);
  combine<<<2500, 256, 0, stream>>>(Y, rowptr, s_src, s_ew, b1, z1, 1);

  // layer 2: Y = z1 @ [W2r | W2o]; z2 = mean-agg(Y_l) + Y_r + b2
  gemm_f16<128><<<157 * 8, 256, 0, stream>>>(z1, w2c, Y, N_NODES, 8, 1024);
  combine<<<2500, 256, 0, stream>>>(Y, rowptr, s_src, s_ew, b2, z2, 0);

  // decoder node-side precompute: AB = z2 @ [Wd1a | Wd1b]  (M=10000, K=512, N=128)
  gemm_f16<64><<<157 * 2, 256, 0, stream>>>(z2, bdt, AB16, N_NODES, 2, 128);

  // per-edge decode
  decode_kernel<<<20000, 256, 0, stream>>>(AB16, eli, expw, Wd1 + 1024 * 64, bd1, Wd2,
                                           bd2, out, NE);
}

// Round 6
// 182.878 us; speedup vs baseline: 2.9706x; 1.0324x over previous
//
#include <hip/hip_runtime.h>

#define N_NODES 10000
#define DIM 512
#define NE 160000

typedef _Float16 f16;
typedef _Float16 f16x2 __attribute__((ext_vector_type(2)));
typedef _Float16 f16x8 __attribute__((ext_vector_type(8)));
typedef float f32x4 __attribute__((ext_vector_type(4)));

__device__ __forceinline__ void gload16(const void* g, void* l) {
  __builtin_amdgcn_global_load_lds((const __attribute__((address_space(1))) void*)g,
                                   (__attribute__((address_space(3))) void*)l, 16, 0, 0);
}

// ---------------- CSR construction ----------------

__global__ __launch_bounds__(256) void zero_deg(int* __restrict__ deg) {
  int i = blockIdx.x * 256 + threadIdx.x;
  if (i < N_NODES) deg[i] = 0;
}

__global__ __launch_bounds__(256) void hist_kernel(const int* __restrict__ dst,
                                                   int* __restrict__ deg, int E) {
  int e = blockIdx.x * 256 + threadIdx.x;
  if (e < E) atomicAdd(&deg[dst[e]], 1);
}

__global__ __launch_bounds__(256) void scan_kernel(const int* __restrict__ deg,
                                                   int* __restrict__ rowptr,
                                                   int* __restrict__ cursor) {
  __shared__ int partial[256];
  const int CH = 40;
  int tid = threadIdx.x;
  int start = tid * CH;
  int sum = 0;
  for (int i = 0; i < CH; ++i) {
    int idx = start + i;
    if (idx < N_NODES) sum += deg[idx];
  }
  partial[tid] = sum;
  __syncthreads();
  if (tid == 0) {
    int run = 0;
    for (int i = 0; i < 256; ++i) { int t = partial[i]; partial[i] = run; run += t; }
  }
  __syncthreads();
  int off = partial[tid];
  for (int i = 0; i < CH; ++i) {
    int idx = start + i;
    if (idx < N_NODES) {
      rowptr[idx] = off;
      cursor[idx] = off;
      off += deg[idx];
    }
  }
  if (tid == 255) rowptr[N_NODES] = off;
}

__global__ __launch_bounds__(256) void scatter_kernel(const int* __restrict__ src,
                                                      const int* __restrict__ dst,
                                                      const float* __restrict__ ew,
                                                      int* __restrict__ cursor,
                                                      int* __restrict__ s_src,
                                                      float* __restrict__ s_ew, int E) {
  int e = blockIdx.x * 256 + threadIdx.x;
  if (e < E) {
    int d = dst[e];
    int p = atomicAdd(&cursor[d], 1);
    s_src[p] = src[e];
    s_ew[p] = ew[e];
  }
}

// ---------------- conversion kernels ----------------

__global__ __launch_bounds__(256) void cast_f16(const float* __restrict__ src,
                                                f16* __restrict__ dst, int n4) {
  int i = blockIdx.x * 256 + threadIdx.x;
  if (i >= n4) return;
  float4 v = ((const float4*)src)[i];
  f16 h0 = (f16)v.x, h1 = (f16)v.y, h2 = (f16)v.z, h3 = (f16)v.w;
  ushort4 hv = {*(ushort*)&h0, *(ushort*)&h1, *(ushort*)&h2, *(ushort*)&h3};
  ((ushort4*)dst)[i] = hv;
}

// transpose 512x512 f32 -> [N][K] fp16, 4 matrices selected by blockIdx.y
__global__ __launch_bounds__(256) void wtrans(const float* s0, const float* s1,
                                              const float* s2, const float* s3,
                                              f16* d0, f16* d1, f16* d2, f16* d3) {
  const float* src; f16* dh;
  switch (blockIdx.y) {
    case 0: src = s0; dh = d0; break;
    case 1: src = s1; dh = d1; break;
    case 2: src = s2; dh = d2; break;
    default: src = s3; dh = d3; break;
  }
  __shared__ float sT[64][65];
  int tile = blockIdx.x;
  int tr = tile >> 3, tc = tile & 7;
  int tid = threadIdx.x;
  for (int i = 0; i < 16; ++i) {
    int lin = i * 256 + tid;
    int r = lin >> 6, c = lin & 63;
    sT[r][c] = src[(size_t)(tr * 64 + r) * 512 + tc * 64 + c];
  }
  __syncthreads();
  for (int i = 0; i < 16; ++i) {
    int lin = i * 256 + tid;
    int n = lin >> 6, k = lin & 63;
    dh[(size_t)(tc * 64 + n) * 512 + tr * 64 + k] = (f16)sT[k][n];
  }
}

// combined decoder weight, transposed: Bt[j][k]: j<64 -> Wd1[k][j], j>=64 -> Wd1[512+k][j-64]
__global__ __launch_bounds__(256) void wd1_build(const float* __restrict__ Wd1,
                                                 f16* __restrict__ bt) {
  int lin = blockIdx.x * 256 + threadIdx.x;
  if (lin >= 128 * 512) return;
  int j = lin >> 9, k = lin & 511;
  bt[lin] = (f16)Wd1[(size_t)(j < 64 ? k : 512 + k) * 64 + (j & 63)];
}

// ---------------- MFMA GEMM: out(f16) = A(f16) @ B(f16)^T ----------------
// A: [M][512] fp16. B: [NB*BN][512] fp16 pre-transposed. Block tile BM x BN,
// 4 waves as 2x2 (wave tile BM/2 x BN/2), BK=32, K=512. m97-style structure.
// Columns >= nsplit go to outB at (col - nsplit); both outputs have stride ldo.
// XCD-chunked bijective block swizzle (T1/m204).

template <int BM, int BN>
__global__ __launch_bounds__(256) void gemm_f16(const f16* __restrict__ A,
                                                const f16* __restrict__ B,
                                                f16* __restrict__ outA,
                                                f16* __restrict__ outB, int M, int NB,
                                                int nsplit, int ldo) {
  constexpr int ASLOTS = BM / 16;
  constexpr int SLOTS = (BM + BN) / 16;
  constexpr int SPW = SLOTS / 4;
  constexpr int MI = BM / 32;
  constexpr int NJ = BN / 32;
  __shared__ char smem[SLOTS * 1024];

  // bijective XCD swizzle: consecutive swz share an XCD; bn varies fastest
  int n = gridDim.x;
  int lin = blockIdx.x;
  int q = n >> 3, r = n & 7, xcd = lin & 7;
  int base = xcd < r ? xcd * (q + 1) : r * (q + 1) + (xcd - r) * q;
  int swz = base + (lin >> 3);
  int bm = (swz / NB) * BM;
  int bn = (swz % NB) * BN;

  int tid = threadIdx.x;
  int w = tid >> 6, l = tid & 63;
  int wr = w & 1, wc = w >> 1;

  f32x4 acc[MI][NJ] = {};

  int lr = l >> 2;        // row within 16-row slot
  int lc = (l & 3) * 8;   // fp16 offset within 32-wide stripe

  for (int k0 = 0; k0 < 512; k0 += 32) {
    __syncthreads();
#pragma unroll
    for (int i = 0; i < SPW; ++i) {
      int s = w * SPW + i;
      const f16* src;
      int grow;
      if (s < ASLOTS) {
        src = A; grow = bm + s * 16 + lr; if (grow > M - 1) grow = M - 1;
      } else {
        src = B; grow = bn + (s - ASLOTS) * 16 + lr;
      }
      gload16(src + (size_t)grow * 512 + k0 + lc, smem + s * 1024);
    }
    __syncthreads();

    int rsel = l & 15;
    int ksb = (l >> 4) * 16;  // byte offset of k-slice
    f16x8 fA[MI], fB[NJ];
#pragma unroll
    for (int i = 0; i < MI; ++i) {
      int ra = wr * (BM / 2) + i * 16 + rsel;
      fA[i] = *(const f16x8*)(smem + ra * 64 + ksb);
    }
#pragma unroll
    for (int j = 0; j < NJ; ++j) {
      int rb = wc * (BN / 2) + j * 16 + rsel;
      fB[j] = *(const f16x8*)(smem + ASLOTS * 1024 + rb * 64 + ksb);
    }
#pragma unroll
    for (int i = 0; i < MI; ++i)
#pragma unroll
      for (int j = 0; j < NJ; ++j)
        acc[i][j] = __builtin_amdgcn_mfma_f32_16x16x32_f16(fA[i], fB[j], acc[i][j], 0, 0, 0);
  }

  // epilogue: C/D layout col = lane&15, row = (lane>>4)*4 + reg
#pragma unroll
  for (int i = 0; i < MI; ++i) {
#pragma unroll
    for (int j = 0; j < NJ; ++j) {
      int col = bn + wc * (BN / 2) + j * 16 + (l & 15);
      f16* outp; int ocol;
      if (col < nsplit) { outp = outA; ocol = col; }
      else              { outp = outB; ocol = col - nsplit; }
#pragma unroll
      for (int rg = 0; rg < 4; ++rg) {
        int row = bm + wr * (BM / 2) + i * 16 + (l >> 4) * 4 + rg;
        if (row < M) outp[(size_t)row * ldo + ocol] = (f16)acc[i][j][rg];
      }
    }
  }
}

// ---------------- combine: z = [relu](mean-gather(Yl) + Yr + bias) --------
// Yl, Yr: [N][512] fp16 (rel-GEMM result / root-GEMM result)

__global__ __launch_bounds__(256) void combine(const f16* __restrict__ Yl,
                                               const f16* __restrict__ Yr,
                                               const int* __restrict__ rowptr,
                                               const int* __restrict__ s_src,
                                               const float* __restrict__ s_ew,
                                               const float* __restrict__ bias,
                                               f16* __restrict__ z, int relu) {
  int wid = (blockIdx.x * blockDim.x + threadIdx.x) >> 6;
  int lane = threadIdx.x & 63;
  if (wid >= N_NODES) return;
  int beg = rowptr[wid], end = rowptr[wid + 1];
  float a0[8] = {0, 0, 0, 0, 0, 0, 0, 0};
  float a1[8] = {0, 0, 0, 0, 0, 0, 0, 0};
  int k = beg;
  for (; k + 3 < end; k += 4) {
    int sA = s_src[k], sB = s_src[k + 1], sC = s_src[k + 2], sD = s_src[k + 3];
    float wA = s_ew[k], wB = s_ew[k + 1], wC = s_ew[k + 2], wD = s_ew[k + 3];
    f16x8 vA = *(const f16x8*)(Yl + (size_t)sA * 512 + lane * 8);
    f16x8 vB = *(const f16x8*)(Yl + (size_t)sB * 512 + lane * 8);
    f16x8 vC = *(const f16x8*)(Yl + (size_t)sC * 512 + lane * 8);
    f16x8 vD = *(const f16x8*)(Yl + (size_t)sD * 512 + lane * 8);
#pragma unroll
    for (int t = 0; t < 8; ++t) {
      a0[t] += (float)vA[t] * wA + (float)vC[t] * wC;
      a1[t] += (float)vB[t] * wB + (float)vD[t] * wD;
    }
  }
  for (; k < end; ++k) {
    int sA = s_src[k];
    float wA = s_ew[k];
    f16x8 vA = *(const f16x8*)(Yl + (size_t)sA * 512 + lane * 8);
#pragma unroll
    for (int t = 0; t < 8; ++t) a0[t] += (float)vA[t] * wA;
  }
  float inv = 1.0f / fmaxf((float)(end - beg), 1.0f);
  f16x8 rt = *(const f16x8*)(Yr + (size_t)wid * 512 + lane * 8);
  float4 b0 = *(const float4*)(bias + lane * 8);
  float4 b1v = *(const float4*)(bias + lane * 8 + 4);
  float bb[8] = {b0.x, b0.y, b0.z, b0.w, b1v.x, b1v.y, b1v.z, b1v.w};
  f16x8 o;
#pragma unroll
  for (int t = 0; t < 8; ++t) {
    float v = (a0[t] + a1[t]) * inv + (float)rt[t] + bb[t];
    if (relu) v = fmaxf(v, 0.0f);
    o[t] = (f16)v;
  }
  *(f16x8*)(z + (size_t)wid * DIM + lane * 8) = o;
}

// ---------------- edge decoder: half-wave (32 lanes) per edge, f16x2 loads --------

__global__ __launch_bounds__(256) void decode_kernel(const f16* __restrict__ AB,
                                                     const int* __restrict__ eli,
                                                     const float* __restrict__ expw,
                                                     const float* __restrict__ wrow,
                                                     const float* __restrict__ bd1,
                                                     const float* __restrict__ Wd2,
                                                     const float* __restrict__ bd2,
                                                     float* __restrict__ out, int E) {
  int wid = blockIdx.x * 8 + (threadIdx.x >> 5);
  int j = threadIdx.x & 31;
  if (wid >= E) return;
  int s = eli[wid];
  int d = eli[E + wid];
  float2 sw = *(const float2*)(wrow + 2 * j);
  float2 sb = *(const float2*)(bd1 + 2 * j);
  float2 s2 = *(const float2*)(Wd2 + 2 * j);
  f16x2 va = *(const f16x2*)(AB + (size_t)s * 128 + 2 * j);
  f16x2 vb = *(const f16x2*)(AB + (size_t)d * 128 + 64 + 2 * j);
  float w = expw[wid];
  float h0 = fmaxf((float)va[0] + (float)vb[0] + w * sw.x + sb.x, 0.0f);
  float h1 = fmaxf((float)va[1] + (float)vb[1] + w * sw.y + sb.y, 0.0f);
  float p = h0 * s2.x + h1 * s2.y;
#pragma unroll
  for (int off = 16; off >= 1; off >>= 1) p += __shfl_xor(p, off);
  if (j == 0) out[wid] = p + bd2[0];
}

// ---------------- launcher ----------------

extern "C" void kernel_launch(void* const* d_in, const int* in_sizes, int n_in,
                              void* d_out, int out_size, void* d_ws, size_t ws_size,
                              hipStream_t stream) {
  const float* x    = (const float*)d_in[0];
  const float* ew   = (const float*)d_in[1];
  const float* expw = (const float*)d_in[2];
  const float* W1r  = (const float*)d_in[3];
  const float* b1   = (const float*)d_in[4];
  const float* W1o  = (const float*)d_in[5];
  const float* W2r  = (const float*)d_in[6];
  const float* b2   = (const float*)d_in[7];
  const float* W2o  = (const float*)d_in[8];
  const float* Wd1  = (const float*)d_in[9];
  const float* bd1  = (const float*)d_in[10];
  const float* Wd2  = (const float*)d_in[11];
  const float* bd2  = (const float*)d_in[12];
  const int* ei     = (const int*)d_in[13];
  const int* eli    = (const int*)d_in[14];
  float* out = (float*)d_out;

  char* ws = (char*)d_ws;
  int* deg    = (int*)(ws + 0);
  int* rowptr = (int*)(ws + 40064);
  int* cursor = (int*)(ws + 80128);
  int* s_src  = (int*)(ws + 120192);
  float* s_ew = (float*)(ws + 760192);
  f16* x16    = (f16*)(ws + 1400192);   // 10.24 MB
  f16* z1     = (f16*)(ws + 11640192);  // 10.24 MB
  f16* z2     = (f16*)(ws + 21880192);  // 10.24 MB
  f16* Yl     = (f16*)(ws + 32120192);  // 10.24 MB
  f16* Yr     = (f16*)(ws + 42360192);  // 10.24 MB
  f16* AB16   = (f16*)(ws + 52600192);  // 2.56 MB
  f16* w1c    = (f16*)(ws + 55160192);  // 1 MB  [1024][512]
  f16* w2c    = (f16*)(ws + 56208768);  // 1 MB
  f16* bdt    = (f16*)(ws + 57257344);  // 128 KB [128][512]

  const int* src = ei;
  const int* dst = ei + NE;

  zero_deg<<<40, 256, 0, stream>>>(deg);
  hist_kernel<<<625, 256, 0, stream>>>(dst, deg, NE);
  scan_kernel<<<1, 256, 0, stream>>>(deg, rowptr, cursor);
  scatter_kernel<<<625, 256, 0, stream>>>(src, dst, ew, cursor, s_src, s_ew, NE);

  // conversions
  cast_f16<<<5000, 256, 0, stream>>>(x, x16, N_NODES * DIM / 4);
  wtrans<<<dim3(64, 4), 256, 0, stream>>>(W1r, W1o, W2r, W2o, w1c, w1c + 512 * 512,
                                          w2c, w2c + 512 * 512);
  wd1_build<<<256, 256, 0, stream>>>(Wd1, bdt);

  // layer 1: [Yl|Yr] = x @ [W1r | W1o]; z1 = relu(mean-agg(Yl) + Yr + b1)
  gemm_f16<128, 128><<<79 * 8, 256, 0, stream>>>(x16, w1c, Yl, Yr, N_NODES, 8, 512, 512);
  combine<<<2500, 256, 0, stream>>>(Yl, Yr, rowptr, s_src, s_ew, b1, z1, 1);

  // layer 2: [Yl|Yr] = z1 @ [W2r | W2o]; z2 = mean-agg(Yl) + Yr + b2
  gemm_f16<128, 128><<<79 * 8, 256, 0, stream>>>(z1, w2c, Yl, Yr, N_NODES, 8, 512, 512);
  combine<<<2500, 256, 0, stream>>>(Yl, Yr, rowptr, s_src, s_ew, b2, z2, 0);

  // decoder node-side precompute: AB = z2 @ [Wd1a | Wd1b]  (M=10000, K=512, N=128)
  gemm_f16<64, 64><<<157 * 2, 256, 0, stream>>>(z2, bdt, AB16, AB16, N_NODES, 2, 128, 128);

  // per-edge decode
  decode_kernel<<<20000, 256, 0, stream>>>(AB16, eli, expw, Wd1 + 1024 * 64, bd1, Wd2,
                                           bd2, out, NE);
}